// Round 8
// baseline (473.240 us; speedup 1.0000x reference)
//
#include <hip/hip_runtime.h>

#define NTOK 49

typedef __attribute__((ext_vector_type(8))) short short8;
typedef __attribute__((ext_vector_type(4))) float f32x4;
typedef __attribute__((ext_vector_type(4))) unsigned short u16x4;

__device__ __forceinline__ unsigned short f2bf(float f) {
  union { float f; unsigned u; } v; v.f = f;
  unsigned r = v.u + 0x7FFFu + ((v.u >> 16) & 1u);  // round-to-nearest-even
  return (unsigned short)(r >> 16);
}

// ---- swizzled LDS index helpers (shorts; granule = 16B = 8 shorts). WRITE sites only ----
__device__ __forceinline__ int qk_ix(int row, int col) {
  int gi = (col >> 3) ^ ((row >> 1) & 3);
  return row * 96 + (gi << 3) + (col & 7);
}
__device__ __forceinline__ int vp_ix(int row, int col) {
  int gi = (col >> 3) ^ (row & 7);
  return row * 64 + (gi << 3) + (col & 7);
}

// ---------------- prep: swizzle weights to bf16 MFMA-fragment order + bias gather ----------------
__global__ void prep_kernel(const float* __restrict__ qkv_w,
                            const float* __restrict__ proj_w,
                            const float* __restrict__ bias_table,
                            const int* __restrict__ rel_index,
                            unsigned short* __restrict__ w_swz,
                            unsigned short* __restrict__ pw_swz,
                            float* __restrict__ bias3)
{
  int idx = blockIdx.x * 256 + threadIdx.x;
  if (idx < 248832) {
    int f = idx >> 9, r = idx & 511;
    int l = r >> 3, j = r & 7;
    int nt = f / 9, ks = f - nt * 9;
    int row = nt * 16 + (l & 15);
    int k = ks * 32 + ((l >> 4) << 3) + j;
    w_swz[idx] = f2bf(qkv_w[row * 288 + k]);
  } else if (idx < 248832 + 27648) {
    int t = idx - 248832;
    int f = t >> 9, r = t & 511;
    int l = r >> 3, j = r & 7;
    int h = f / 18, rem = f - h * 18;
    int nt = rem / 3, ks = rem - nt * 3;
    int c = nt * 16 + (l & 15);
    int d = ks * 32 + ((l >> 4) << 3) + j;
    pw_swz[t] = f2bf(proj_w[c * 288 + h * 96 + d]);
  } else if (idx < 248832 + 27648 + 7203) {
    int t = idx - (248832 + 27648);
    int h = t / 2401, r = t - h * 2401;
    bias3[t] = bias_table[rel_index[r] * 3 + h];
  }
}

// ---------------- fused window attention, 8 waves, swizzled LDS, prefetched ----------------
#define A_OFF 0
#define Q_OFF 18432
#define K_OFF 23136
#define VT_OFF 27840
#define P_OFF 33984
#define SMEM_TOT 38080   // 76160 bytes -> 2 blocks/CU

__global__ __attribute__((amdgpu_flat_work_group_size(512, 512), amdgpu_waves_per_eu(4, 4)))
void wattn_kernel(const float* __restrict__ x, const float* __restrict__ y,
                  const float* __restrict__ z, const float* __restrict__ mask,
                  const float* __restrict__ qkv_b, const float* __restrict__ proj_b,
                  const unsigned short* __restrict__ w_swz,
                  const unsigned short* __restrict__ pw_swz,
                  const float* __restrict__ bias3,
                  float* __restrict__ out, int nW)
{
  __shared__ unsigned short smem[SMEM_TOT];
  const int b = blockIdx.x;
  const int tid = threadIdx.x;
  const int w = tid >> 6;        // 0..7
  const int lane = tid & 63;
  const int g = lane >> 4;
  const int cl = lane & 15;
  const int widx = b % nW;
  const int t4 = w & 3;          // row-tile for S/PV/proj
  const int hf = w >> 2;         // half split

  // per-thread affine swizzle constants (reads)
  const int gx = ((g ^ ((cl >> 1) & 3)) << 3);   // A/Q/K granule adj (shorts)
  const int c2 = (cl >> 2) & 1;
  const int gv = ((g ^ (cl & 3)) << 3);          // Vt/P granule adj (shorts)
  const int s0 = c2 << 5;                        // Vt/P ks=0 offset (shorts)
  const int s1 = 32 - s0;                        // Vt/P ks=1 offset

  // ---- stage concat(x,y,z) -> LDS bf16, swizzled, all 9 loads in flight ----
  {
    const int row = tid >> 3;
    const int t7 = tid & 7;
    const int lb = row * 288 + (((t7 >> 1) ^ ((row >> 1) & 3)) << 3) + (t7 & 1) * 4;
    const size_t gb = ((size_t)b * NTOK + row) * 96 + t7 * 4;
    float4 v[9];
    #pragma unroll
    for (int seg = 0; seg < 3; ++seg) {
      const float* sp = (seg == 0) ? x : ((seg == 1) ? y : z);
      #pragma unroll
      for (int k3 = 0; k3 < 3; ++k3) {
        v[seg * 3 + k3] = make_float4(0.f, 0.f, 0.f, 0.f);
        if (row < NTOK) v[seg * 3 + k3] = *(const float4*)(sp + gb + k3 * 32);
      }
    }
    #pragma unroll
    for (int i = 0; i < 9; ++i) {
      u16x4 s;
      s[0] = f2bf(v[i].x); s[1] = f2bf(v[i].y); s[2] = f2bf(v[i].z); s[3] = f2bf(v[i].w);
      *(u16x4*)&smem[lb + (i / 3) * 96 + (i % 3) * 32] = s;
    }
  }

  // QKV tile constants: wave owns tiles 2w, 2w+1 (0..15) + pass2 V tile (16/17)
  const int tA = 2 * w, tB = 2 * w + 1;
  const int sA = (tA >= 12) ? 2 : ((tA >= 6) ? 1 : 0);
  const int sB = (tB >= 12) ? 2 : ((tB >= 6) ? 1 : 0);
  const int dA = tA - 6 * sA, dB = tB - 6 * sB;
  const int mw = w & 3;
  const int d2 = 4 + (w >> 2);

  const unsigned short* abase = &smem[A_OFF + cl * 288 + gx];
  const unsigned short* abm   = &smem[A_OFF + (mw * 16 + cl) * 288 + gx];

  f32x4 outacc[3];
  #pragma unroll
  for (int i = 0; i < 3; ++i) outacc[i] = f32x4{0.f, 0.f, 0.f, 0.f};

  __syncthreads();

  #pragma unroll 1
  for (int h = 0; h < 3; ++h) {
    __syncthreads();  // prev head's Q/K/Vt/P/O reads complete

    // ---- QKV block 1: tile tA + pass2 V-tile chain, depth-2 weight prefetch ----
    {
      const unsigned short* wp  = w_swz + (size_t)(sA * 18 + h * 6 + dA) * 9 * 512 + lane * 8;
      const unsigned short* wpC = w_swz + (size_t)(36 + h * 6 + d2) * 9 * 512 + lane * 8;
      f32x4 acc[4];
      #pragma unroll
      for (int m = 0; m < 4; ++m) acc[m] = f32x4{0.f, 0.f, 0.f, 0.f};
      f32x4 acc2 = f32x4{0.f, 0.f, 0.f, 0.f};
      short8 w0  = *(const short8*)(wp);
      short8 w1  = *(const short8*)(wp + 512);
      short8 cw0 = *(const short8*)(wpC);
      short8 cw1 = *(const short8*)(wpC + 512);
      #pragma unroll 2
      for (int ks = 0; ks < 9; ++ks) {
        const int pf = (ks + 2 > 8) ? 8 : ks + 2;
        short8 w2  = *(const short8*)(wp  + pf * 512);
        short8 cw2 = *(const short8*)(wpC + pf * 512);
        short8 af0 = *(const short8*)(abase + 0 * 4608 + ks * 32);
        short8 af1 = *(const short8*)(abase + 1 * 4608 + ks * 32);
        short8 af2 = *(const short8*)(abase + 2 * 4608 + ks * 32);
        short8 af3 = *(const short8*)(abase + 3 * 4608 + ks * 32);
        short8 afm = *(const short8*)(abm + ks * 32);
        acc[0] = __builtin_amdgcn_mfma_f32_16x16x32_bf16(af0, w0, acc[0], 0, 0, 0);
        acc[1] = __builtin_amdgcn_mfma_f32_16x16x32_bf16(af1, w0, acc[1], 0, 0, 0);
        acc[2] = __builtin_amdgcn_mfma_f32_16x16x32_bf16(af2, w0, acc[2], 0, 0, 0);
        acc[3] = __builtin_amdgcn_mfma_f32_16x16x32_bf16(af3, w0, acc[3], 0, 0, 0);
        acc2   = __builtin_amdgcn_mfma_f32_16x16x32_bf16(afm, cw0, acc2, 0, 0, 0);
        w0 = w1; w1 = w2; cw0 = cw1; cw1 = cw2;
      }
      // writeback tile tA
      {
        float bq = qkv_b[sA * 288 + h * 96 + dA * 16 + cl];
        if (sA == 2) {
          #pragma unroll
          for (int m = 0; m < 4; ++m) {
            u16x4 pk;
            #pragma unroll
            for (int r = 0; r < 4; ++r) pk[r] = f2bf(acc[m][r] + bq);
            *(u16x4*)&smem[VT_OFF + vp_ix(dA * 16 + cl, m * 16 + (g << 2))] = pk;
          }
        } else {
          const int off = sA ? K_OFF : Q_OFF;
          const float sc = sA ? 1.f : 0.1767766952966369f;
          #pragma unroll
          for (int m = 0; m < 4; ++m) {
            #pragma unroll
            for (int r = 0; r < 4; ++r) {
              int row = m * 16 + (g << 2) + r;
              if (row < NTOK)
                smem[off + qk_ix(row, dA * 16 + cl)] = f2bf((acc[m][r] + bq) * sc);
            }
          }
        }
      }
      // writeback pass2 V tile
      {
        float bq = qkv_b[2 * 288 + h * 96 + d2 * 16 + cl];
        u16x4 pk;
        #pragma unroll
        for (int r = 0; r < 4; ++r) pk[r] = f2bf(acc2[r] + bq);
        *(u16x4*)&smem[VT_OFF + vp_ix(d2 * 16 + cl, mw * 16 + (g << 2))] = pk;
      }
    }

    // ---- QKV block 2: tile tB, depth-2 weight prefetch ----
    {
      const unsigned short* wp = w_swz + (size_t)(sB * 18 + h * 6 + dB) * 9 * 512 + lane * 8;
      f32x4 acc[4];
      #pragma unroll
      for (int m = 0; m < 4; ++m) acc[m] = f32x4{0.f, 0.f, 0.f, 0.f};
      short8 w0 = *(const short8*)(wp);
      short8 w1 = *(const short8*)(wp + 512);
      #pragma unroll 2
      for (int ks = 0; ks < 9; ++ks) {
        const int pf = (ks + 2 > 8) ? 8 : ks + 2;
        short8 w2  = *(const short8*)(wp + pf * 512);
        short8 af0 = *(const short8*)(abase + 0 * 4608 + ks * 32);
        short8 af1 = *(const short8*)(abase + 1 * 4608 + ks * 32);
        short8 af2 = *(const short8*)(abase + 2 * 4608 + ks * 32);
        short8 af3 = *(const short8*)(abase + 3 * 4608 + ks * 32);
        acc[0] = __builtin_amdgcn_mfma_f32_16x16x32_bf16(af0, w0, acc[0], 0, 0, 0);
        acc[1] = __builtin_amdgcn_mfma_f32_16x16x32_bf16(af1, w0, acc[1], 0, 0, 0);
        acc[2] = __builtin_amdgcn_mfma_f32_16x16x32_bf16(af2, w0, acc[2], 0, 0, 0);
        acc[3] = __builtin_amdgcn_mfma_f32_16x16x32_bf16(af3, w0, acc[3], 0, 0, 0);
        w0 = w1; w1 = w2;
      }
      float bq = qkv_b[sB * 288 + h * 96 + dB * 16 + cl];
      if (sB == 2) {
        #pragma unroll
        for (int m = 0; m < 4; ++m) {
          u16x4 pk;
          #pragma unroll
          for (int r = 0; r < 4; ++r) pk[r] = f2bf(acc[m][r] + bq);
          *(u16x4*)&smem[VT_OFF + vp_ix(dB * 16 + cl, m * 16 + (g << 2))] = pk;
        }
      } else {
        const int off = sB ? K_OFF : Q_OFF;
        const float sc = sB ? 1.f : 0.1767766952966369f;
        #pragma unroll
        for (int m = 0; m < 4; ++m) {
          #pragma unroll
          for (int r = 0; r < 4; ++r) {
            int row = m * 16 + (g << 2) + r;
            if (row < NTOK)
              smem[off + qk_ix(row, dB * 16 + cl)] = f2bf((acc[m][r] + bq) * sc);
          }
        }
      }
    }
    __syncthreads();

    // ---- prefetch bias+mask for my 2 softmax rows (hidden under S MFMAs) ----
    float bi[2][4], mk[2][4];
    #pragma unroll
    for (int rr = 0; rr < 2; ++rr) {
      int n = t4 * 16 + (g << 2) + 2 * hf + rr;
      int nn = n < NTOK ? n : NTOK - 1;
      const float* brow = bias3 + h * 2401 + nn * 49;
      const float* mrow = mask + ((size_t)widx * NTOK + nn) * NTOK;
      #pragma unroll
      for (int nt = 0; nt < 4; ++nt) {
        int mm = nt * 16 + cl;
        mm = mm < NTOK ? mm : NTOK - 1;
        bi[rr][nt] = brow[mm];
        mk[rr][nt] = mrow[mm];
      }
    }

    // ---- S = Q K^T ----
    f32x4 sacc[4];
    #pragma unroll
    for (int nt = 0; nt < 4; ++nt) sacc[nt] = f32x4{0.f, 0.f, 0.f, 0.f};
    {
      const unsigned short* qbase = &smem[Q_OFF + (t4 * 16 + cl) * 96 + gx];
      const unsigned short* kbase = &smem[K_OFF + cl * 96 + gx];
      #pragma unroll
      for (int ks = 0; ks < 3; ++ks) {
        short8 aq = *(const short8*)(qbase + ks * 32);
        #pragma unroll
        for (int nt = 0; nt < 4; ++nt) {
          short8 bk = *(const short8*)(kbase + nt * (16 * 96) + ks * 32);
          sacc[nt] = __builtin_amdgcn_mfma_f32_16x16x32_bf16(aq, bk, sacc[nt], 0, 0, 0);
        }
      }
    }

    // ---- softmax: wave handles rows r in {2hf, 2hf+1} ----
    #pragma unroll
    for (int r = 0; r < 4; ++r) {
      if ((r >> 1) != hf) continue;     // uniform; r compile-time
      const int rr = r & 1;
      int n = t4 * 16 + (g << 2) + r;
      float vals[4];
      float mx = -1e30f;
      #pragma unroll
      for (int nt = 0; nt < 4; ++nt) {
        int m = nt * 16 + cl;
        float sv = -1e30f;
        if (m < NTOK) sv = sacc[nt][r] + bi[rr][nt] + mk[rr][nt];
        vals[nt] = sv;
        mx = fmaxf(mx, sv);
      }
      mx = fmaxf(mx, __shfl_xor(mx, 1));
      mx = fmaxf(mx, __shfl_xor(mx, 2));
      mx = fmaxf(mx, __shfl_xor(mx, 4));
      mx = fmaxf(mx, __shfl_xor(mx, 8));
      float sum = 0.f;
      #pragma unroll
      for (int nt = 0; nt < 4; ++nt) {
        float e = __expf(vals[nt] - mx);
        vals[nt] = e;
        sum += e;
      }
      sum += __shfl_xor(sum, 1);
      sum += __shfl_xor(sum, 2);
      sum += __shfl_xor(sum, 4);
      sum += __shfl_xor(sum, 8);
      float inv = 1.f / sum;
      #pragma unroll
      for (int nt = 0; nt < 4; ++nt)
        smem[P_OFF + vp_ix(n, nt * 16 + cl)] = f2bf(vals[nt] * inv);
    }
    __syncthreads();

    // ---- O = P @ V ----
    f32x4 oacc[3];
    #pragma unroll
    for (int jj = 0; jj < 3; ++jj) oacc[jj] = f32x4{0.f, 0.f, 0.f, 0.f};
    {
      const unsigned short* pbase = &smem[P_OFF + (t4 * 16 + cl) * 64 + gv];
      const unsigned short* vbase = &smem[VT_OFF + (hf * 3 * 16 + cl) * 64 + gv];
      #pragma unroll
      for (int ks = 0; ks < 2; ++ks) {
        const int ko = ks ? s1 : s0;
        short8 ap = *(const short8*)(pbase + ko);
        #pragma unroll
        for (int jj = 0; jj < 3; ++jj) {
          short8 bv = *(const short8*)(vbase + jj * (16 * 64) + ko);
          oacc[jj] = __builtin_amdgcn_mfma_f32_16x16x32_bf16(ap, bv, oacc[jj], 0, 0, 0);
        }
      }
    }

    // ---- prefetch ALL 9 proj-weight fragments (absorbed at the barrier) ----
    short8 bp[3][3];
    {
      const unsigned short* pwb = pw_swz + (size_t)(h * 6 + hf * 3) * 3 * 512 + lane * 8;
      #pragma unroll
      for (int jj = 0; jj < 3; ++jj)
        #pragma unroll
        for (int ks = 0; ks < 3; ++ks)
          bp[jj][ks] = *(const short8*)(pwb + (size_t)(jj * 3 + ks) * 512);
    }

    // ---- O writeback (K region) ----
    #pragma unroll
    for (int jj = 0; jj < 3; ++jj) {
      #pragma unroll
      for (int r = 0; r < 4; ++r) {
        int row = t4 * 16 + (g << 2) + r;
        if (row < NTOK)
          smem[K_OFF + qk_ix(row, (hf * 3 + jj) * 16 + cl)] = f2bf(oacc[jj][r]);
      }
    }
    __syncthreads();

    // ---- proj partial ----
    {
      const unsigned short* obase = &smem[K_OFF + (t4 * 16 + cl) * 96 + gx];
      #pragma unroll
      for (int ks = 0; ks < 3; ++ks) {
        short8 ao = *(const short8*)(obase + ks * 32);
        #pragma unroll
        for (int jj = 0; jj < 3; ++jj)
          outacc[jj] = __builtin_amdgcn_mfma_f32_16x16x32_bf16(ao, bp[jj][ks], outacc[jj], 0, 0, 0);
      }
    }
  }

  // ---- epilogue ----
  #pragma unroll
  for (int jj = 0; jj < 3; ++jj) {
    float pb = proj_b[(hf * 3 + jj) * 16 + cl];
    #pragma unroll
    for (int r = 0; r < 4; ++r) {
      int n = t4 * 16 + (g << 2) + r;
      if (n < NTOK)
        out[((size_t)b * NTOK + n) * 96 + (hf * 3 + jj) * 16 + cl] = outacc[jj][r] + pb;
    }
  }
}

extern "C" void kernel_launch(void* const* d_in, const int* in_sizes, int n_in,
                              void* d_out, int out_size, void* d_ws, size_t ws_size,
                              hipStream_t stream) {
  const float* x          = (const float*)d_in[0];
  const float* y          = (const float*)d_in[1];
  const float* z          = (const float*)d_in[2];
  const float* mask       = (const float*)d_in[3];
  const float* qkv_w      = (const float*)d_in[4];
  const float* qkv_b      = (const float*)d_in[5];
  const float* proj_w     = (const float*)d_in[6];
  const float* proj_b     = (const float*)d_in[7];
  const float* bias_table = (const float*)d_in[8];
  const int*   rel_index  = (const int*)d_in[9];

  int B  = in_sizes[0] / (NTOK * 96);
  int nW = in_sizes[3] / (NTOK * NTOK);

  unsigned short* w_swz  = (unsigned short*)d_ws;
  unsigned short* pw_swz = w_swz + 248832;
  float*          bias3  = (float*)(pw_swz + 27648);

  prep_kernel<<<1109, 256, 0, stream>>>(qkv_w, proj_w, bias_table, rel_index,
                                        w_swz, pw_swz, bias3);
  wattn_kernel<<<B, 512, 0, stream>>>(x, y, z, mask, qkv_b, proj_b,
                                      w_swz, pw_swz, bias3, (float*)d_out, nW);
}

// Round 9
// 340.618 us; speedup vs baseline: 1.3894x; 1.3894x over previous
//
#include <hip/hip_runtime.h>

#define NTOK 49

typedef __attribute__((ext_vector_type(8))) short short8;
typedef __attribute__((ext_vector_type(4))) float f32x4;
typedef __attribute__((ext_vector_type(4))) unsigned short u16x4;

__device__ __forceinline__ unsigned short f2bf(float f) {
  union { float f; unsigned u; } v; v.f = f;
  unsigned r = v.u + 0x7FFFu + ((v.u >> 16) & 1u);  // round-to-nearest-even
  return (unsigned short)(r >> 16);
}

// ---- swizzled LDS index helpers (shorts; granule = 16B = 8 shorts). WRITE sites only ----
__device__ __forceinline__ int qk_ix(int row, int col) {
  int gi = (col >> 3) ^ ((row >> 1) & 3);
  return row * 96 + (gi << 3) + (col & 7);
}
__device__ __forceinline__ int vp_ix(int row, int col) {
  int gi = (col >> 3) ^ (row & 7);
  return row * 64 + (gi << 3) + (col & 7);
}

// ---------------- prep 1: Q/K weight swizzle (tiles 0..35) + bias gather ----------------
__global__ void prep_kernel(const float* __restrict__ qkv_w,
                            const float* __restrict__ bias_table,
                            const int* __restrict__ rel_index,
                            unsigned short* __restrict__ w_swz,
                            float* __restrict__ bias3)
{
  int idx = blockIdx.x * 256 + threadIdx.x;
  if (idx < 165888) {                       // 36 tiles (q,k) * 9 ks * 512
    int f = idx >> 9, r = idx & 511;
    int l = r >> 3, j = r & 7;
    int nt = f / 9, ks = f - nt * 9;        // nt 0..35 -> q,k rows 0..575
    int row = nt * 16 + (l & 15);
    int k = ks * 32 + ((l >> 4) << 3) + j;
    w_swz[idx] = f2bf(qkv_w[row * 288 + k]);
  } else if (idx < 165888 + 7203) {
    int t = idx - 165888;
    int h = t / 2401, r = t - h * 2401;
    bias3[t] = bias_table[rel_index[r] * 3 + h];
  }
}

// ---------------- prep 2: fold proj into V:  WVP_h = P_h @ Wv_h  (fp32), swizzled bf16 ----------------
// Also cb[d] = proj_b[d] + sum_h P_h @ bv_h.
__global__ void prep2_kernel(const float* __restrict__ qkv_w,
                             const float* __restrict__ qkv_b,
                             const float* __restrict__ proj_w,
                             const float* __restrict__ proj_b,
                             unsigned short* __restrict__ w_swz,
                             float* __restrict__ cb)
{
  int idx = blockIdx.x * 256 + threadIdx.x;
  if (idx < 82944) {                        // 18 tiles * 9 ks * 512
    int f = idx >> 9, r = idx & 511;
    int l = r >> 3, j = r & 7;
    int hn = f / 9, ks = f - hn * 9;        // hn = h*6+ntd
    int h = hn / 6, ntd = hn - h * 6;
    int d = ntd * 16 + (l & 15);            // output dim 0..95
    int k = ks * 32 + ((l >> 4) << 3) + j;  // input dim 0..287
    const float* pr = proj_w + d * 288 + h * 96;
    const float* wr = qkv_w + (size_t)(576 + h * 96) * 288 + k;
    float s = 0.f;
    #pragma unroll 8
    for (int t = 0; t < 96; ++t) s += pr[t] * wr[(size_t)t * 288];
    w_swz[165888 + idx] = f2bf(s);          // tiles 36..53
  } else if (idx < 82944 + 96) {
    int d = idx - 82944;
    float s = proj_b[d];
    #pragma unroll 1
    for (int h = 0; h < 3; ++h) {
      const float* pr = proj_w + d * 288 + h * 96;
      const float* bv = qkv_b + 576 + h * 96;
      #pragma unroll 8
      for (int t = 0; t < 96; ++t) s += pr[t] * bv[t];
    }
    cb[d] = s;
  }
}

// ---------------- fused window attention, 8 waves, swizzled LDS, proj folded ----------------
#define A_OFF 0
#define Q_OFF 18432
#define K_OFF 23136
#define VT_OFF 27840
#define P_OFF 33984
#define SMEM_TOT 38080   // 76160 bytes -> 2 blocks/CU

__global__ __launch_bounds__(512, 4)
void wattn_kernel(const float* __restrict__ x, const float* __restrict__ y,
                  const float* __restrict__ z, const float* __restrict__ mask,
                  const float* __restrict__ qkv_b, const float* __restrict__ cb,
                  const unsigned short* __restrict__ w_swz,
                  const float* __restrict__ bias3,
                  float* __restrict__ out, int nW)
{
  __shared__ unsigned short smem[SMEM_TOT];
  const int b = blockIdx.x;
  const int tid = threadIdx.x;
  const int w = tid >> 6;        // 0..7
  const int lane = tid & 63;
  const int g = lane >> 4;
  const int cl = lane & 15;
  const int widx = b % nW;
  const int t4 = w & 3;          // row-tile for S/PV
  const int hf = w >> 2;         // half split

  // per-thread affine swizzle constants (reads)
  const int gx = ((g ^ ((cl >> 1) & 3)) << 3);   // A/Q/K granule adj (shorts)
  const int c2 = (cl >> 2) & 1;
  const int gv = ((g ^ (cl & 3)) << 3);          // Vt/P granule adj (shorts)
  const int s0 = c2 << 5;                        // Vt/P ks=0 offset (shorts)
  const int s1 = 32 - s0;                        // Vt/P ks=1 offset

  // ---- stage concat(x,y,z) -> LDS bf16, swizzled (rows>=49 zero), low pressure ----
  {
    const int row = tid >> 3;                       // 0..63
    const int t7 = tid & 7;
    const int lb = row * 288 + (((t7 >> 1) ^ ((row >> 1) & 3)) << 3) + (t7 & 1) * 4;
    const size_t gb = ((size_t)b * NTOK + row) * 96 + t7 * 4;
    #pragma unroll 1
    for (int seg = 0; seg < 3; ++seg) {
      const float* sp = (seg == 0) ? x : ((seg == 1) ? y : z);
      float4 v0 = make_float4(0.f, 0.f, 0.f, 0.f);
      float4 v1 = v0, v2 = v0;
      if (row < NTOK) {
        const float* p = sp + gb;
        v0 = *(const float4*)(p);
        v1 = *(const float4*)(p + 32);
        v2 = *(const float4*)(p + 64);
      }
      u16x4 w0, w1, w2;
      w0[0]=f2bf(v0.x); w0[1]=f2bf(v0.y); w0[2]=f2bf(v0.z); w0[3]=f2bf(v0.w);
      w1[0]=f2bf(v1.x); w1[1]=f2bf(v1.y); w1[2]=f2bf(v1.z); w1[3]=f2bf(v1.w);
      w2[0]=f2bf(v2.x); w2[1]=f2bf(v2.y); w2[2]=f2bf(v2.z); w2[3]=f2bf(v2.w);
      int o = lb + seg * 96;
      *(u16x4*)&smem[o]      = w0;
      *(u16x4*)&smem[o + 32] = w1;
      *(u16x4*)&smem[o + 64] = w2;
    }
  }

  // QKV pass-1 tile constants (tiles 0..15): wave owns 2w, 2w+1
  const int tA = 2 * w, tB = 2 * w + 1;
  const int sA = (tA >= 12) ? 2 : ((tA >= 6) ? 1 : 0);
  const int sB = (tB >= 12) ? 2 : ((tB >= 6) ? 1 : 0);
  const int dA = tA - 6 * sA, dB = tB - 6 * sB;
  // pass-2: all-V tiles 16,17 split by m-tile across 8 waves
  const int mw = w & 3;
  const int d2 = 4 + (w >> 2);

  f32x4 outacc[3];
  #pragma unroll
  for (int i = 0; i < 3; ++i) outacc[i] = f32x4{0.f, 0.f, 0.f, 0.f};

  __syncthreads();

  #pragma unroll 1
  for (int h = 0; h < 3; ++h) {
    // all reads of previous head's Q/K/Vt/P complete before overwrite
    __syncthreads();

    // ---- QKV pass 1: two tiles per wave, SEQUENTIAL, 1-deep weight prefetch ----
    {
      const unsigned short* abase = &smem[A_OFF + cl * 288 + gx];
      #pragma unroll 1
      for (int t = 0; t < 2; ++t) {
        const int s   = t ? sB : sA;
        const int ntd = t ? dB : dA;
        const unsigned short* wp = w_swz + (size_t)(s * 18 + h * 6 + ntd) * 9 * 512 + lane * 8;
        f32x4 acc[4];
        #pragma unroll
        for (int m = 0; m < 4; ++m) acc[m] = f32x4{0.f, 0.f, 0.f, 0.f};
        short8 bf = *(const short8*)(wp);
        #pragma unroll 1
        for (int ks = 0; ks < 8; ++ks) {
          short8 bfn = *(const short8*)(wp + (ks + 1) * 512);
          short8 af0 = *(const short8*)(abase + 0 * (16 * 288) + ks * 32);
          short8 af1 = *(const short8*)(abase + 1 * (16 * 288) + ks * 32);
          short8 af2 = *(const short8*)(abase + 2 * (16 * 288) + ks * 32);
          short8 af3 = *(const short8*)(abase + 3 * (16 * 288) + ks * 32);
          acc[0] = __builtin_amdgcn_mfma_f32_16x16x32_bf16(af0, bf, acc[0], 0, 0, 0);
          acc[1] = __builtin_amdgcn_mfma_f32_16x16x32_bf16(af1, bf, acc[1], 0, 0, 0);
          acc[2] = __builtin_amdgcn_mfma_f32_16x16x32_bf16(af2, bf, acc[2], 0, 0, 0);
          acc[3] = __builtin_amdgcn_mfma_f32_16x16x32_bf16(af3, bf, acc[3], 0, 0, 0);
          bf = bfn;
        }
        {
          short8 af0 = *(const short8*)(abase + 0 * (16 * 288) + 8 * 32);
          short8 af1 = *(const short8*)(abase + 1 * (16 * 288) + 8 * 32);
          short8 af2 = *(const short8*)(abase + 2 * (16 * 288) + 8 * 32);
          short8 af3 = *(const short8*)(abase + 3 * (16 * 288) + 8 * 32);
          acc[0] = __builtin_amdgcn_mfma_f32_16x16x32_bf16(af0, bf, acc[0], 0, 0, 0);
          acc[1] = __builtin_amdgcn_mfma_f32_16x16x32_bf16(af1, bf, acc[1], 0, 0, 0);
          acc[2] = __builtin_amdgcn_mfma_f32_16x16x32_bf16(af2, bf, acc[2], 0, 0, 0);
          acc[3] = __builtin_amdgcn_mfma_f32_16x16x32_bf16(af3, bf, acc[3], 0, 0, 0);
        }
        // writeback tile t
        if (s == 2) {                     // V': no bias (folded into cb)
          #pragma unroll
          for (int m = 0; m < 4; ++m) {
            u16x4 pk;
            #pragma unroll
            for (int r = 0; r < 4; ++r) pk[r] = f2bf(acc[m][r]);
            *(u16x4*)&smem[VT_OFF + vp_ix(ntd * 16 + cl, m * 16 + (g << 2))] = pk;
          }
        } else {
          float bq = qkv_b[s * 288 + h * 96 + ntd * 16 + cl];
          const int off = s ? K_OFF : Q_OFF;
          const float sc = s ? 1.f : 0.1767766952966369f;
          #pragma unroll
          for (int m = 0; m < 4; ++m) {
            #pragma unroll
            for (int r = 0; r < 4; ++r) {
              int row = m * 16 + (g << 2) + r;
              if (row < NTOK)
                smem[off + qk_ix(row, ntd * 16 + cl)] = f2bf((acc[m][r] + bq) * sc);
            }
          }
        }
      }
    }

    // ---- QKV pass 2: V' tiles 16,17, one m-tile per wave, prefetched ----
    {
      f32x4 acc2 = f32x4{0, 0, 0, 0};
      const unsigned short* wpC = w_swz + (size_t)(36 + h * 6 + d2) * 9 * 512 + lane * 8;
      const unsigned short* abase2 = &smem[A_OFF + (mw * 16 + cl) * 288 + gx];
      short8 bf = *(const short8*)(wpC);
      #pragma unroll 1
      for (int ks = 0; ks < 8; ++ks) {
        short8 bfn = *(const short8*)(wpC + (ks + 1) * 512);
        short8 af = *(const short8*)(abase2 + ks * 32);
        acc2 = __builtin_amdgcn_mfma_f32_16x16x32_bf16(af, bf, acc2, 0, 0, 0);
        bf = bfn;
      }
      {
        short8 af = *(const short8*)(abase2 + 8 * 32);
        acc2 = __builtin_amdgcn_mfma_f32_16x16x32_bf16(af, bf, acc2, 0, 0, 0);
      }
      u16x4 pk;
      #pragma unroll
      for (int r = 0; r < 4; ++r) pk[r] = f2bf(acc2[r]);
      *(u16x4*)&smem[VT_OFF + vp_ix(d2 * 16 + cl, mw * 16 + (g << 2))] = pk;
    }
    __syncthreads();

    // ---- S = Q K^T (wave-pair duplicates its row-tile) ----
    f32x4 sacc[4];
    #pragma unroll
    for (int nt = 0; nt < 4; ++nt) sacc[nt] = f32x4{0.f, 0.f, 0.f, 0.f};
    {
      const unsigned short* qbase = &smem[Q_OFF + (t4 * 16 + cl) * 96 + gx];
      const unsigned short* kbase = &smem[K_OFF + cl * 96 + gx];
      #pragma unroll 1
      for (int ks = 0; ks < 3; ++ks) {
        short8 aq = *(const short8*)(qbase + ks * 32);
        #pragma unroll
        for (int nt = 0; nt < 4; ++nt) {
          short8 bk = *(const short8*)(kbase + nt * (16 * 96) + ks * 32);
          sacc[nt] = __builtin_amdgcn_mfma_f32_16x16x32_bf16(aq, bk, sacc[nt], 0, 0, 0);
        }
      }
    }

    // ---- softmax: wave handles rows r in {2hf, 2hf+1} of its tile ----
    #pragma unroll
    for (int r = 0; r < 4; ++r) {
      if ((r >> 1) != hf) continue;     // uniform; r compile-time
      int n = t4 * 16 + (g << 2) + r;
      int nn = n < NTOK ? n : NTOK - 1;
      const float* brow = bias3 + h * 2401 + nn * 49;
      const float* mrow = mask + ((size_t)widx * NTOK + nn) * NTOK;
      float vals[4];
      float mx = -1e30f;
      #pragma unroll
      for (int nt = 0; nt < 4; ++nt) {
        int m = nt * 16 + cl;
        int mm = m < NTOK ? m : NTOK - 1;
        float sv = -1e30f;
        if (m < NTOK) sv = sacc[nt][r] + brow[mm] + mrow[mm];
        vals[nt] = sv;
        mx = fmaxf(mx, sv);
      }
      mx = fmaxf(mx, __shfl_xor(mx, 1));
      mx = fmaxf(mx, __shfl_xor(mx, 2));
      mx = fmaxf(mx, __shfl_xor(mx, 4));
      mx = fmaxf(mx, __shfl_xor(mx, 8));
      float sum = 0.f;
      #pragma unroll
      for (int nt = 0; nt < 4; ++nt) {
        float e = __expf(vals[nt] - mx);
        vals[nt] = e;
        sum += e;
      }
      sum += __shfl_xor(sum, 1);
      sum += __shfl_xor(sum, 2);
      sum += __shfl_xor(sum, 4);
      sum += __shfl_xor(sum, 8);
      float inv = 1.f / sum;
      #pragma unroll
      for (int nt = 0; nt < 4; ++nt)
        smem[P_OFF + vp_ix(n, nt * 16 + cl)] = f2bf(vals[nt] * inv);
    }
    __syncthreads();

    // ---- out partial: outacc += P @ V'  (proj folded; direct fp32 accumulation) ----
    {
      const unsigned short* pbase = &smem[P_OFF + (t4 * 16 + cl) * 64 + gv];
      const unsigned short* vbase = &smem[VT_OFF + (hf * 3 * 16 + cl) * 64 + gv];
      #pragma unroll
      for (int ks = 0; ks < 2; ++ks) {
        const int ko = ks ? s1 : s0;
        short8 ap = *(const short8*)(pbase + ko);
        #pragma unroll
        for (int jj = 0; jj < 3; ++jj) {
          short8 bv = *(const short8*)(vbase + jj * (16 * 64) + ko);
          outacc[jj] = __builtin_amdgcn_mfma_f32_16x16x32_bf16(ap, bv, outacc[jj], 0, 0, 0);
        }
      }
    }
  }

  // ---- epilogue: + cb (folded proj_b + proj(bv)), store fp32 ----
  #pragma unroll
  for (int jj = 0; jj < 3; ++jj) {
    float pb = cb[(hf * 3 + jj) * 16 + cl];
    #pragma unroll
    for (int r = 0; r < 4; ++r) {
      int n = t4 * 16 + (g << 2) + r;
      if (n < NTOK)
        out[((size_t)b * NTOK + n) * 96 + (hf * 3 + jj) * 16 + cl] = outacc[jj][r] + pb;
    }
  }
}

extern "C" void kernel_launch(void* const* d_in, const int* in_sizes, int n_in,
                              void* d_out, int out_size, void* d_ws, size_t ws_size,
                              hipStream_t stream) {
  const float* x          = (const float*)d_in[0];
  const float* y          = (const float*)d_in[1];
  const float* z          = (const float*)d_in[2];
  const float* mask       = (const float*)d_in[3];
  const float* qkv_w      = (const float*)d_in[4];
  const float* qkv_b      = (const float*)d_in[5];
  const float* proj_w     = (const float*)d_in[6];
  const float* proj_b     = (const float*)d_in[7];
  const float* bias_table = (const float*)d_in[8];
  const int*   rel_index  = (const int*)d_in[9];

  int B  = in_sizes[0] / (NTOK * 96);
  int nW = in_sizes[3] / (NTOK * NTOK);

  unsigned short* w_swz = (unsigned short*)d_ws;        // 248832 shorts (54 tiles)
  float*          bias3 = (float*)(w_swz + 248832);     // 7203 floats
  float*          cbv   = bias3 + 7203;                 // 96 floats

  prep_kernel<<<677, 256, 0, stream>>>(qkv_w, bias_table, rel_index, w_swz, bias3);
  prep2_kernel<<<325, 256, 0, stream>>>(qkv_w, qkv_b, proj_w, proj_b, w_swz, cbv);
  wattn_kernel<<<B, 512, 0, stream>>>(x, y, z, mask, qkv_b, cbv,
                                      w_swz, bias3, (float*)d_out, nW);
}